// Round 15
// baseline (104.940 us; speedup 1.0000x reference)
//
#include <hip/hip_runtime.h>
#include <stdint.h>

#define Tn 2048
#define Nn 2048
#define Dn 256
#define NHEAD 8           // flattened b*4+h
#define NKI 16            // K-steps of 128 int8 over N=2048

typedef __attribute__((ext_vector_type(8))) short short8;
typedef __attribute__((ext_vector_type(4))) float f32x4;
typedef __attribute__((ext_vector_type(4))) int i32x4;
typedef __attribute__((ext_vector_type(16))) int i32x16;

__device__ __forceinline__ uint16_t f2bf(float x) {
  uint32_t u = __float_as_uint(x);
  return (uint16_t)((u + 0x7FFFu + ((u >> 16) & 1u)) >> 16);   // RNE
}

__device__ __forceinline__ void gload_lds16(const void* g, void* l) {
  __builtin_amdgcn_global_load_lds((const __attribute__((address_space(1))) uint32_t*)g,
                                   (__attribute__((address_space(3))) uint32_t*)l,
                                   16, 0, 0);
}

// ------- RoPE + per-row int8 quantization, ONE WAVE PER ROW (+ folded V transpose) -------
__global__ __launch_bounds__(256) void rope_kernel(const float* __restrict__ Q,
                                                   uint8_t* __restrict__ QR,
                                                   float* __restrict__ Sc,
                                                   const float* __restrict__ V,
                                                   uint16_t* __restrict__ VT) {
  const int tid = threadIdx.x;
  const int bx = blockIdx.x;             // 0..4095
  // folded vt: 4096*256 = 2^20 elems of VT[b][d][t]
  {
    int o = bx * 256 + tid;
    int vt = o & (Tn - 1);
    int vd = (o >> 11) & (Dn - 1);
    int vb = o >> 19;
    VT[o] = f2bf(V[((size_t)vb * Tn + vt) * Dn + vd]);
  }
  const int wv = tid >> 6, L = tid & 63;
  const int row = bx * 4 + wv;           // g*2048 + t
  const int t = row & (Tn - 1);
  const float* src = Q + (size_t)row * Nn;

  float o[32];
  float am = 1e-8f;
#pragma unroll
  for (int k = 0; k < 8; ++k) {
    const float4 q = *(const float4*)(src + L * 4 + 256 * k);   // coalesced
    int p0 = 2 * L + 128 * k;            // pair index of elems (0,1)
    float f0 = exp2f(-(float)p0 * (1.0f / 64.0f)) * 0.15915494309189535f;
    float f1 = exp2f(-(float)(p0 + 1) * (1.0f / 64.0f)) * 0.15915494309189535f;
    float x0 = (float)t * f0, x1 = (float)t * f1;
    float r0 = x0 - floorf(x0), r1 = x1 - floorf(x1);           // revolutions in [0,1)
    float s0 = __builtin_amdgcn_sinf(r0), c0 = __builtin_amdgcn_cosf(r0);
    float s1 = __builtin_amdgcn_sinf(r1), c1 = __builtin_amdgcn_cosf(r1);
    float o0 = q.x * c0 - q.y * s0;
    float o1 = q.y * c0 + q.x * s0;
    float o2 = q.z * c1 - q.w * s1;
    float o3 = q.w * c1 + q.z * s1;
    o[4 * k] = o0; o[4 * k + 1] = o1; o[4 * k + 2] = o2; o[4 * k + 3] = o3;
    am = fmaxf(am, fmaxf(fmaxf(fabsf(o0), fabsf(o1)), fmaxf(fabsf(o2), fabsf(o3))));
  }
#pragma unroll
  for (int off = 32; off > 0; off >>= 1) am = fmaxf(am, __shfl_xor(am, off));
  const float sc = 127.0f / am;
#pragma unroll
  for (int k = 0; k < 8; ++k) {
    int q0 = min(127, max(-127, (int)rintf(o[4 * k] * sc)));
    int q1 = min(127, max(-127, (int)rintf(o[4 * k + 1] * sc)));
    int q2 = min(127, max(-127, (int)rintf(o[4 * k + 2] * sc)));
    int q3 = min(127, max(-127, (int)rintf(o[4 * k + 3] * sc)));
    uint32_t pk = (uint32_t)(q0 & 255) | ((uint32_t)(q1 & 255) << 8) |
                  ((uint32_t)(q2 & 255) << 16) | ((uint32_t)q3 << 24);
    *(uint32_t*)(QR + (size_t)row * Nn + L * 4 + 256 * k) = pk;
  }
  if (L == 0) Sc[row] = am * (1.0f / 127.0f);
}

// ------- K1: S = tril(QR QR^T), int8 MFMA 32x32x32, 128x128 tiles, m97 structure -------
// A/B fragment (K=32): lane l -> row l&31, k = (l>>5)*16 + [0..15] (16 B).
// C/D (A=J,B=I swap): i = lane&31, j = (reg&3) + 8*(reg>>2) + 4*(lane>>5).
__global__ __launch_bounds__(256, 4) void qkt_kernel(const uint8_t* __restrict__ QR,
                                                     const float* __restrict__ Sc,
                                                     uint16_t* __restrict__ S) {
  __shared__ __align__(16) char lds0[32768];   // I-panel 16K | J-panel 16K (128 rows x 128 B)
  const int bx = blockIdx.x;
  const int g = bx & 7;
  int p = bx >> 3;
  int ti, tj; bool diag;
  if (p < 120) {
    ti = 1; while (p >= ti) { p -= ti; ++ti; }
    tj = p; diag = false;
  } else {
    ti = p - 120; tj = ti; diag = true;
  }

  const int tid = threadIdx.x;
  const int wv = tid >> 6, l = tid & 63;
  const int l31 = l & 31, lh = l >> 5;         // row-in-frag, k-group
  const int wi = wv >> 1;            // i half (64 rows)
  const int wj = wv & 1;             // j half (64 cols)
  const bool active = !(diag && wi == 0 && wj == 1);
  const bool needmask = diag && (wi == wj);

  const uint8_t* QRh = QR + (size_t)g * Tn * Nn;
  const int r0 = tid >> 3;                       // staging row 0..31
  const int scg = (tid & 7) ^ (r0 & 7);          // inverse-swizzled source chunk (16 B)
  const uint8_t* gI = QRh + (size_t)(ti * 128 + r0) * Nn + scg * 16;
  const uint8_t* gJ = QRh + (size_t)(tj * 128 + r0) * Nn + scg * 16;

  char* bufI = lds0;
  char* bufJ = lds0 + 16384;

  i32x16 acc[2][2];
#pragma unroll
  for (int mi = 0; mi < 2; ++mi)
#pragma unroll
    for (int nj = 0; nj < 2; ++nj)
#pragma unroll
      for (int r = 0; r < 16; ++r) acc[mi][nj][r] = 0;

  for (int k0 = 0; k0 < NKI; ++k0) {
    const int ke = k0 * 128;         // byte offset within row
    __syncthreads();
#pragma unroll
    for (int rnd = 0; rnd < 4; ++rnd) {
      gload_lds16(gI + (size_t)rnd * 32 * Nn + ke, bufI + rnd * 4096 + wv * 1024);
      if (!diag) gload_lds16(gJ + (size_t)rnd * 32 * Nn + ke, bufJ + rnd * 4096 + wv * 1024);
    }
    __syncthreads();
    if (active) {
      const char* bI = bufI;
      const char* bJ = diag ? bufI : bufJ;
#pragma unroll
      for (int ks = 0; ks < 4; ++ks) {   // four K=32 slices of the 128-B window
        i32x4 ifr[2], jfr[2];
#pragma unroll
        for (int mi = 0; mi < 2; ++mi) {
          int row = wi * 64 + mi * 32 + l31;
          int c = (ks * 2 + lh) ^ (row & 7);
          ifr[mi] = *(const i32x4*)(bI + row * 128 + c * 16);
        }
#pragma unroll
        for (int nj = 0; nj < 2; ++nj) {
          int row = wj * 64 + nj * 32 + l31;
          int c = (ks * 2 + lh) ^ (row & 7);
          jfr[nj] = *(const i32x4*)(bJ + row * 128 + c * 16);
        }
        __builtin_amdgcn_s_setprio(1);
#pragma unroll
        for (int mi = 0; mi < 2; ++mi)
#pragma unroll
          for (int nj = 0; nj < 2; ++nj)
            acc[mi][nj] = __builtin_amdgcn_mfma_i32_32x32x32_i8(jfr[nj], ifr[mi], acc[mi][nj], 0, 0, 0);
        __builtin_amdgcn_s_setprio(0);
      }
    }
  }

  // epilogue: rescale by row scales, mask diag, pack bf16
  // frag (mi,nj): i = wi*64+mi*32+l31 (fixed/lane); reg quad q covers j = nj*32 + 8q + 4*lh + {0..3}
  uint16_t* Sh = S + (size_t)g * Tn * Tn;
  const float* ScI = Sc + g * Tn + ti * 128;
  const float* ScJ = Sc + g * Tn + tj * 128;
  if (active) {
#pragma unroll
    for (int mi = 0; mi < 2; ++mi) {
      int iloc = wi * 64 + mi * 32 + l31;
      float si = ScI[iloc];
#pragma unroll
      for (int nj = 0; nj < 2; ++nj) {
        i32x16 a = acc[mi][nj];
#pragma unroll
        for (int q = 0; q < 4; ++q) {
          int jloc = wj * 64 + nj * 32 + q * 8 + 4 * lh;
          float4 sj = *(const float4*)(ScJ + jloc);
          float v0 = (float)a[4 * q + 0] * si * sj.x;
          float v1 = (float)a[4 * q + 1] * si * sj.y;
          float v2 = (float)a[4 * q + 2] * si * sj.z;
          float v3 = (float)a[4 * q + 3] * si * sj.w;
          if (needmask) {
            if (jloc + 0 >= iloc) v0 = 0.f;
            if (jloc + 1 >= iloc) v1 = 0.f;
            if (jloc + 2 >= iloc) v2 = 0.f;
            if (jloc + 3 >= iloc) v3 = 0.f;
          }
          uint32_t lo = (uint32_t)f2bf(v0) | ((uint32_t)f2bf(v1) << 16);
          uint32_t hi = (uint32_t)f2bf(v2) | ((uint32_t)f2bf(v3) << 16);
          *(uint2*)(Sh + (size_t)(ti * 128 + iloc) * Tn + tj * 128 + jloc) = make_uint2(lo, hi);
        }
      }
    }
  } else {
#pragma unroll
    for (int mi = 0; mi < 2; ++mi)
#pragma unroll
      for (int nj = 0; nj < 2; ++nj)
#pragma unroll
        for (int q = 0; q < 4; ++q) {
          int iloc = wi * 64 + mi * 32 + l31;
          int jloc = wj * 64 + nj * 32 + q * 8 + 4 * lh;
          *(uint2*)(Sh + (size_t)(ti * 128 + iloc) * Tn + tj * 128 + jloc) = make_uint2(0u, 0u);
        }
  }
}

// ---------------- K2: O = S * V (via VT), 64 i x 128 d tiles, balanced causal ----------------
// grid 512: g = bx&7; jid = bx>>3 (0..63): dh = jid&1, ti = 31-(jid>>1) (longest first).
// T4 counted-vmcnt pipeline, depth 2: 3 LDS buffers (72 KB), steady-state waits vmcnt(3).
__global__ __launch_bounds__(512) void pv_kernel(const uint16_t* __restrict__ S,
                                                 const uint16_t* __restrict__ VT,
                                                 float* __restrict__ O) {
  extern __shared__ char lds[];
  const int bx = blockIdx.x;
  const int g = bx & 7;
  const int b = g >> 2;
  const int jid = bx >> 3;           // 0..63
  const int dh = jid & 1;
  const int ti = 31 - (jid >> 1);    // 64-row i-tile, longest first
  const int nsteps = ti + 1;

  const int tid = threadIdx.x;
  const int w = tid >> 6, l = tid & 63, l15 = l & 15, lg = l >> 4;
  const int ih = w >> 2;             // i 32-half (of 64 rows)
  const int dq = w & 3;              // d 32-quarter (of 128)

  const uint16_t* Sh = S + (size_t)g * Tn * Tn;
  const uint16_t* VTb = VT + (size_t)b * Dn * Tn;
  const int r0 = tid >> 3;           // 0..63
  const int scg = (tid & 7) ^ (r0 & 7);
  const uint16_t* gS = Sh + (size_t)(ti * 64 + r0) * Tn + scg * 8;
  const uint16_t* gV = VTb + (size_t)(dh * 128 + r0) * Tn + scg * 8;

  f32x4 acc[2][2];
#pragma unroll
  for (int ma = 0; ma < 2; ++ma)
#pragma unroll
    for (int ni = 0; ni < 2; ++ni) acc[ma][ni] = (f32x4){0.f, 0.f, 0.f, 0.f};

  auto stage = [&](int ke, int bsel) {
    char* bufS = lds + bsel * 24576;
    char* bufV = bufS + 8192;
    gload_lds16(gS + ke, bufS + w * 1024);                       // S: 64 rows x 128B
    gload_lds16(gV + ke, bufV + w * 1024);                       // V rows 0..63
    gload_lds16(gV + (size_t)64 * Tn + ke, bufV + 8192 + w * 1024);  // V rows 64..127
  };

  stage(0, 0);
  if (nsteps > 1) stage(64, 1);

  int cur = 0;                       // jt % 3
  for (int jt = 0; jt < nsteps; ++jt) {
    if (jt + 1 < nsteps) { asm volatile("s_waitcnt vmcnt(3)" ::: "memory"); }
    else                 { asm volatile("s_waitcnt vmcnt(0)" ::: "memory"); }
    __builtin_amdgcn_s_barrier();
    if (jt + 2 < nsteps) {
      int nb = cur + 2; if (nb >= 3) nb -= 3;
      stage((jt + 2) * 64, nb);
    }
    const char* bS = lds + cur * 24576;
    const char* bV = bS + 8192;
#pragma unroll
    for (int ks = 0; ks < 2; ++ks) {
      short8 av[2], bs[2];
#pragma unroll
      for (int ma = 0; ma < 2; ++ma) {
        int row = dq * 32 + ma * 16 + l15;       // d-local row (128)
        int c = (ks * 4 + lg) ^ (row & 7);
        av[ma] = *(const short8*)(bV + row * 128 + c * 16);
      }
#pragma unroll
      for (int ni = 0; ni < 2; ++ni) {
        int row = ih * 32 + ni * 16 + l15;       // i-local row (64)
        int c = (ks * 4 + lg) ^ (row & 7);
        bs[ni] = *(const short8*)(bS + row * 128 + c * 16);
      }
      __builtin_amdgcn_s_setprio(1);
#pragma unroll
      for (int ma = 0; ma < 2; ++ma)
#pragma unroll
        for (int ni = 0; ni < 2; ++ni)
          acc[ma][ni] = __builtin_amdgcn_mfma_f32_16x16x32_bf16(av[ma], bs[ni], acc[ma][ni], 0, 0, 0);
      __builtin_amdgcn_s_setprio(0);
    }
    ++cur; if (cur >= 3) cur = 0;
  }

  // store: col(l15) = i, rows(lg*4+rr) = d -> 16B fp32 stores
  float* Oh = O + (size_t)g * Tn * Dn;
#pragma unroll
  for (int ma = 0; ma < 2; ++ma)
#pragma unroll
    for (int ni = 0; ni < 2; ++ni) {
      int iloc = ih * 32 + ni * 16 + l15;
      int d0 = dh * 128 + dq * 32 + ma * 16 + lg * 4;
      *(f32x4*)(Oh + (size_t)(ti * 64 + iloc) * Dn + d0) = acc[ma][ni];
    }
}

extern "C" void kernel_launch(void* const* d_in, const int* in_sizes, int n_in,
                              void* d_out, int out_size, void* d_ws, size_t ws_size,
                              hipStream_t stream) {
  const float* Q = (const float*)d_in[0];
  const float* V = (const float*)d_in[1];
  float* O = (float*)d_out;

  // ws: QRi8 [8][T][N] (32 MiB) | Sc fp32 [8][T] (64 KiB) | VT bf16 (2 MiB) | S bf16 (64 MiB)
  uint8_t* QRw = (uint8_t*)d_ws;
  float*   ScW = (float*)(QRw + (size_t)NHEAD * Tn * Nn);
  uint16_t* VTw = (uint16_t*)(ScW + (size_t)NHEAD * Tn);
  uint16_t* Sw  = VTw + (size_t)2 * Dn * Tn;

  hipFuncSetAttribute((const void*)pv_kernel, hipFuncAttributeMaxDynamicSharedMemorySize, 73728);

  rope_kernel<<<4096, 256, 0, stream>>>(Q, QRw, ScW, V, VTw);
  qkt_kernel<<<1088, 256, 0, stream>>>(QRw, ScW, Sw);
  pv_kernel<<<512, 512, 73728, stream>>>(Sw, VTw, O);
}

// Round 16
// 95.111 us; speedup vs baseline: 1.1033x; 1.1033x over previous
//
#include <hip/hip_runtime.h>
#include <stdint.h>

#define Tn 2048
#define Nn 2048
#define Dn 256
#define NHEAD 8           // flattened b*4+h
#define NKI 16            // K-steps of 128 int8 over N=2048

typedef __attribute__((ext_vector_type(8))) short short8;
typedef __attribute__((ext_vector_type(4))) float f32x4;
typedef __attribute__((ext_vector_type(4))) int i32x4;

__device__ __forceinline__ uint16_t f2bf(float x) {
  uint32_t u = __float_as_uint(x);
  return (uint16_t)((u + 0x7FFFu + ((u >> 16) & 1u)) >> 16);   // RNE
}

__device__ __forceinline__ void gload_lds16(const void* g, void* l) {
  __builtin_amdgcn_global_load_lds((const __attribute__((address_space(1))) uint32_t*)g,
                                   (__attribute__((address_space(3))) uint32_t*)l,
                                   16, 0, 0);
}

// ------- RoPE + per-row int8 quantization, ONE WAVE PER ROW (+ folded V transpose) -------
__global__ __launch_bounds__(256) void rope_kernel(const float* __restrict__ Q,
                                                   uint8_t* __restrict__ QR,
                                                   float* __restrict__ Sc,
                                                   const float* __restrict__ V,
                                                   uint16_t* __restrict__ VT) {
  const int tid = threadIdx.x;
  const int bx = blockIdx.x;             // 0..4095
  // folded vt: 4096*256 = 2^20 elems of VT[b][d][t]
  {
    int o = bx * 256 + tid;
    int vt = o & (Tn - 1);
    int vd = (o >> 11) & (Dn - 1);
    int vb = o >> 19;
    VT[o] = f2bf(V[((size_t)vb * Tn + vt) * Dn + vd]);
  }
  const int wv = tid >> 6, L = tid & 63;
  const int row = bx * 4 + wv;           // g*2048 + t
  const int t = row & (Tn - 1);
  const float* src = Q + (size_t)row * Nn;

  float o[32];
  float am = 1e-8f;
#pragma unroll
  for (int k = 0; k < 8; ++k) {
    const float4 q = *(const float4*)(src + L * 4 + 256 * k);   // coalesced
    int p0 = 2 * L + 128 * k;            // pair index of elems (0,1)
    float f0 = exp2f(-(float)p0 * (1.0f / 64.0f)) * 0.15915494309189535f;
    float f1 = exp2f(-(float)(p0 + 1) * (1.0f / 64.0f)) * 0.15915494309189535f;
    float x0 = (float)t * f0, x1 = (float)t * f1;
    float r0 = x0 - floorf(x0), r1 = x1 - floorf(x1);           // revolutions in [0,1)
    float s0 = __builtin_amdgcn_sinf(r0), c0 = __builtin_amdgcn_cosf(r0);
    float s1 = __builtin_amdgcn_sinf(r1), c1 = __builtin_amdgcn_cosf(r1);
    float o0 = q.x * c0 - q.y * s0;
    float o1 = q.y * c0 + q.x * s0;
    float o2 = q.z * c1 - q.w * s1;
    float o3 = q.w * c1 + q.z * s1;
    o[4 * k] = o0; o[4 * k + 1] = o1; o[4 * k + 2] = o2; o[4 * k + 3] = o3;
    am = fmaxf(am, fmaxf(fmaxf(fabsf(o0), fabsf(o1)), fmaxf(fabsf(o2), fabsf(o3))));
  }
#pragma unroll
  for (int off = 32; off > 0; off >>= 1) am = fmaxf(am, __shfl_xor(am, off));
  const float sc = 127.0f / am;
#pragma unroll
  for (int k = 0; k < 8; ++k) {
    int q0 = min(127, max(-127, (int)rintf(o[4 * k] * sc)));
    int q1 = min(127, max(-127, (int)rintf(o[4 * k + 1] * sc)));
    int q2 = min(127, max(-127, (int)rintf(o[4 * k + 2] * sc)));
    int q3 = min(127, max(-127, (int)rintf(o[4 * k + 3] * sc)));
    uint32_t pk = (uint32_t)(q0 & 255) | ((uint32_t)(q1 & 255) << 8) |
                  ((uint32_t)(q2 & 255) << 16) | ((uint32_t)q3 << 24);
    *(uint32_t*)(QR + (size_t)row * Nn + L * 4 + 256 * k) = pk;
  }
  if (L == 0) Sc[row] = am * (1.0f / 127.0f);
}

// ------- K1: S = tril(QR QR^T), int8 MFMA (16x16x64), 128x128 tiles, m97 structure -------
__global__ __launch_bounds__(256, 4) void qkt_kernel(const uint8_t* __restrict__ QR,
                                                     const float* __restrict__ Sc,
                                                     uint16_t* __restrict__ S) {
  __shared__ __align__(16) char lds0[32768];   // I-panel 16K | J-panel 16K (128 rows x 128 B)
  const int bx = blockIdx.x;
  const int g = bx & 7;
  int p = bx >> 3;
  int ti, tj; bool diag;
  if (p < 120) {
    ti = 1; while (p >= ti) { p -= ti; ++ti; }
    tj = p; diag = false;
  } else {
    ti = p - 120; tj = ti; diag = true;
  }

  const int tid = threadIdx.x;
  const int wv = tid >> 6, l = tid & 63, l15 = l & 15, lg = l >> 4;
  const int wi = wv >> 1;            // i half (64 rows)
  const int wj = wv & 1;             // j half (64 cols)
  const bool active = !(diag && wi == 0 && wj == 1);
  const bool needmask = diag && (wi == wj);

  const uint8_t* QRh = QR + (size_t)g * Tn * Nn;
  const int r0 = tid >> 3;                       // staging row 0..31
  const int scg = (tid & 7) ^ (r0 & 7);          // inverse-swizzled source chunk (16 B)
  const uint8_t* gI = QRh + (size_t)(ti * 128 + r0) * Nn + scg * 16;
  const uint8_t* gJ = QRh + (size_t)(tj * 128 + r0) * Nn + scg * 16;

  char* bufI = lds0;
  char* bufJ = lds0 + 16384;

  i32x4 acc[4][4];
#pragma unroll
  for (int mi = 0; mi < 4; ++mi)
#pragma unroll
    for (int nj = 0; nj < 4; ++nj) acc[mi][nj] = (i32x4){0, 0, 0, 0};

  for (int k0 = 0; k0 < NKI; ++k0) {
    const int ke = k0 * 128;         // byte offset within row
    __syncthreads();
#pragma unroll
    for (int rnd = 0; rnd < 4; ++rnd) {
      gload_lds16(gI + (size_t)rnd * 32 * Nn + ke, bufI + rnd * 4096 + wv * 1024);
      if (!diag) gload_lds16(gJ + (size_t)rnd * 32 * Nn + ke, bufJ + rnd * 4096 + wv * 1024);
    }
    __syncthreads();
    if (active) {
      const char* bI = bufI;
      const char* bJ = diag ? bufI : bufJ;
#pragma unroll
      for (int ks = 0; ks < 2; ++ks) {   // two K=64 halves of the 128-B window
        i32x4 ifr[4], jfr[4];
#pragma unroll
        for (int mi = 0; mi < 4; ++mi) {
          int row = wi * 64 + mi * 16 + l15;
          int c = (ks * 4 + lg) ^ (row & 7);
          ifr[mi] = *(const i32x4*)(bI + row * 128 + c * 16);
        }
#pragma unroll
        for (int nj = 0; nj < 4; ++nj) {
          int row = wj * 64 + nj * 16 + l15;
          int c = (ks * 4 + lg) ^ (row & 7);
          jfr[nj] = *(const i32x4*)(bJ + row * 128 + c * 16);
        }
        __builtin_amdgcn_s_setprio(1);
#pragma unroll
        for (int mi = 0; mi < 4; ++mi)
#pragma unroll
          for (int nj = 0; nj < 4; ++nj)
            acc[mi][nj] = __builtin_amdgcn_mfma_i32_16x16x64_i8(jfr[nj], ifr[mi], acc[mi][nj], 0, 0, 0);
        __builtin_amdgcn_s_setprio(0);
      }
    }
  }

  // epilogue: rescale by row scales, mask diag, pack bf16
  uint16_t* Sh = S + (size_t)g * Tn * Tn;
  const float* ScI = Sc + g * Tn + ti * 128;
  const float* ScJ = Sc + g * Tn + tj * 128;
  if (active) {
#pragma unroll
    for (int mi = 0; mi < 4; ++mi) {
      int iloc = wi * 64 + mi * 16 + l15;
      float si = ScI[iloc];
#pragma unroll
      for (int nj = 0; nj < 4; ++nj) {
        int jloc = wj * 64 + nj * 16 + lg * 4;
        float4 sj = *(const float4*)(ScJ + jloc);
        i32x4 a = acc[mi][nj];
        float v0 = (float)a[0] * si * sj.x;
        float v1 = (float)a[1] * si * sj.y;
        float v2 = (float)a[2] * si * sj.z;
        float v3 = (float)a[3] * si * sj.w;
        if (needmask) {
          if (jloc + 0 >= iloc) v0 = 0.f;
          if (jloc + 1 >= iloc) v1 = 0.f;
          if (jloc + 2 >= iloc) v2 = 0.f;
          if (jloc + 3 >= iloc) v3 = 0.f;
        }
        uint32_t lo = (uint32_t)f2bf(v0) | ((uint32_t)f2bf(v1) << 16);
        uint32_t hi = (uint32_t)f2bf(v2) | ((uint32_t)f2bf(v3) << 16);
        *(uint2*)(Sh + (size_t)(ti * 128 + iloc) * Tn + tj * 128 + jloc) = make_uint2(lo, hi);
      }
    }
  } else {
#pragma unroll
    for (int mi = 0; mi < 4; ++mi)
#pragma unroll
      for (int nj = 0; nj < 4; ++nj) {
        int iloc = wi * 64 + mi * 16 + l15;
        int jloc = wj * 64 + nj * 16 + lg * 4;
        *(uint2*)(Sh + (size_t)(ti * 128 + iloc) * Tn + tj * 128 + jloc) = make_uint2(0u, 0u);
      }
  }
}

// ---------------- K2: O = S * V (via VT), 64 i x 128 d tiles, balanced causal ----------------
// grid 512: g = bx&7; jid = bx>>3 (0..63): dh = jid&1, ti = 31-(jid>>1) (longest first).
// T4 counted-vmcnt pipeline, depth 2: 3 LDS buffers (72 KB), steady-state waits vmcnt(3).
__global__ __launch_bounds__(512) void pv_kernel(const uint16_t* __restrict__ S,
                                                 const uint16_t* __restrict__ VT,
                                                 float* __restrict__ O) {
  extern __shared__ char lds[];
  const int bx = blockIdx.x;
  const int g = bx & 7;
  const int b = g >> 2;
  const int jid = bx >> 3;           // 0..63
  const int dh = jid & 1;
  const int ti = 31 - (jid >> 1);    // 64-row i-tile, longest first
  const int nsteps = ti + 1;

  const int tid = threadIdx.x;
  const int w = tid >> 6, l = tid & 63, l15 = l & 15, lg = l >> 4;
  const int ih = w >> 2;             // i 32-half (of 64 rows)
  const int dq = w & 3;              // d 32-quarter (of 128)

  const uint16_t* Sh = S + (size_t)g * Tn * Tn;
  const uint16_t* VTb = VT + (size_t)b * Dn * Tn;
  const int r0 = tid >> 3;           // 0..63
  const int scg = (tid & 7) ^ (r0 & 7);
  const uint16_t* gS = Sh + (size_t)(ti * 64 + r0) * Tn + scg * 8;
  const uint16_t* gV = VTb + (size_t)(dh * 128 + r0) * Tn + scg * 8;

  f32x4 acc[2][2];
#pragma unroll
  for (int ma = 0; ma < 2; ++ma)
#pragma unroll
    for (int ni = 0; ni < 2; ++ni) acc[ma][ni] = (f32x4){0.f, 0.f, 0.f, 0.f};

  auto stage = [&](int ke, int bsel) {
    char* bufS = lds + bsel * 24576;
    char* bufV = bufS + 8192;
    gload_lds16(gS + ke, bufS + w * 1024);                       // S: 64 rows x 128B
    gload_lds16(gV + ke, bufV + w * 1024);                       // V rows 0..63
    gload_lds16(gV + (size_t)64 * Tn + ke, bufV + 8192 + w * 1024);  // V rows 64..127
  };

  stage(0, 0);
  if (nsteps > 1) stage(64, 1);

  int cur = 0;                       // jt % 3
  for (int jt = 0; jt < nsteps; ++jt) {
    if (jt + 1 < nsteps) { asm volatile("s_waitcnt vmcnt(3)" ::: "memory"); }
    else                 { asm volatile("s_waitcnt vmcnt(0)" ::: "memory"); }
    __builtin_amdgcn_s_barrier();
    if (jt + 2 < nsteps) {
      int nb = cur + 2; if (nb >= 3) nb -= 3;
      stage((jt + 2) * 64, nb);
    }
    const char* bS = lds + cur * 24576;
    const char* bV = bS + 8192;
#pragma unroll
    for (int ks = 0; ks < 2; ++ks) {
      short8 av[2], bs[2];
#pragma unroll
      for (int ma = 0; ma < 2; ++ma) {
        int row = dq * 32 + ma * 16 + l15;       // d-local row (128)
        int c = (ks * 4 + lg) ^ (row & 7);
        av[ma] = *(const short8*)(bV + row * 128 + c * 16);
      }
#pragma unroll
      for (int ni = 0; ni < 2; ++ni) {
        int row = ih * 32 + ni * 16 + l15;       // i-local row (64)
        int c = (ks * 4 + lg) ^ (row & 7);
        bs[ni] = *(const short8*)(bS + row * 128 + c * 16);
      }
      __builtin_amdgcn_s_setprio(1);
#pragma unroll
      for (int ma = 0; ma < 2; ++ma)
#pragma unroll
        for (int ni = 0; ni < 2; ++ni)
          acc[ma][ni] = __builtin_amdgcn_mfma_f32_16x16x32_bf16(av[ma], bs[ni], acc[ma][ni], 0, 0, 0);
      __builtin_amdgcn_s_setprio(0);
    }
    ++cur; if (cur >= 3) cur = 0;
  }

  // store: col(l15) = i, rows(lg*4+rr) = d -> 16B fp32 stores
  float* Oh = O + (size_t)g * Tn * Dn;
#pragma unroll
  for (int ma = 0; ma < 2; ++ma)
#pragma unroll
    for (int ni = 0; ni < 2; ++ni) {
      int iloc = ih * 32 + ni * 16 + l15;
      int d0 = dh * 128 + dq * 32 + ma * 16 + lg * 4;
      *(f32x4*)(Oh + (size_t)(ti * 64 + iloc) * Dn + d0) = acc[ma][ni];
    }
}

extern "C" void kernel_launch(void* const* d_in, const int* in_sizes, int n_in,
                              void* d_out, int out_size, void* d_ws, size_t ws_size,
                              hipStream_t stream) {
  const float* Q = (const float*)d_in[0];
  const float* V = (const float*)d_in[1];
  float* O = (float*)d_out;

  // ws: QRi8 [8][T][N] (32 MiB) | Sc fp32 [8][T] (64 KiB) | VT bf16 (2 MiB) | S bf16 (64 MiB)
  uint8_t* QRw = (uint8_t*)d_ws;
  float*   ScW = (float*)(QRw + (size_t)NHEAD * Tn * Nn);
  uint16_t* VTw = (uint16_t*)(ScW + (size_t)NHEAD * Tn);
  uint16_t* Sw  = VTw + (size_t)2 * Dn * Tn;

  hipFuncSetAttribute((const void*)pv_kernel, hipFuncAttributeMaxDynamicSharedMemorySize, 73728);

  rope_kernel<<<4096, 256, 0, stream>>>(Q, QRw, ScW, V, VTw);
  qkt_kernel<<<1088, 256, 0, stream>>>(QRw, ScW, Sw);
  pv_kernel<<<512, 512, 73728, stream>>>(Sw, VTw, O);
}